// Round 6
// baseline (284.861 us; speedup 1.0000x reference)
//
#include <hip/hip_runtime.h>
#include <hip/hip_fp16.h>
#include <math.h>

#define NSLOTS 4096
#define DIM    128
#define HDIM   1024
#define NTOK   16384   // 4 * 4096
#define SCALE  0.08838834764831845f  // 1/sqrt(128)
#define REPS   1e-10f

typedef __attribute__((ext_vector_type(8))) short bf16x8;
typedef __attribute__((ext_vector_type(4))) float f32x4;

typedef __attribute__((address_space(1))) const void* as1cv;
typedef __attribute__((address_space(3))) void* as3v;

// ---- packed (score | 4095-slot) helpers -----------------------------------
// Low 12 mantissa bits replaced by (4095-slot): float compare = score desc,
// then slot asc. fp32 rescue re-ranks the candidate pool exactly, so only
// pool membership matters. Top-8-per-lane + per-half top-16 guarantees the
// true bf16-top-8 is always in the pool (≤7 elements outrank it anywhere).
__device__ __forceinline__ float pack_score(float biased, unsigned inv_idx) {
    return __uint_as_float((__float_as_uint(biased) & 0xFFFFF000u) | inv_idx);
}
#define PACK_NEG_INF __uint_as_float(0xFF7FF000u)   // ~ -FLT_MAX, valid finite

// Branchless insert into ascending sorted r[0..7] (r[7]=max), drop min.
__device__ __forceinline__ void ins_packed(float (&r)[8], float x) {
    #pragma unroll
    for (int i = 0; i < 7; ++i) r[i] = __builtin_amdgcn_fmed3f(r[i], x, r[i + 1]);
    r[7] = fmaxf(r[7], x);
}

// Pop-merge 4 kseg-lanes' sorted top-8 (32 values) -> sorted top-16 (desc,
// packed) into LDS. Group = lanes {l, l^16, l^32, l^48}.
__device__ __forceinline__ void merge_out16(float (&r)[8], int kseg, float* outS) {
    float hv = r[7];
    #pragma unroll
    for (int rnd = 0; rnd < 16; ++rnd) {
        float bv = hv;
        bv = fmaxf(bv, __shfl_xor(bv, 16, 64));
        bv = fmaxf(bv, __shfl_xor(bv, 32, 64));
        if ((rnd >> 2) == kseg) outS[rnd] = bv;   // each kseg-lane writes 4
        if (hv == bv) {   // my head won (packed values distinct in group): pop
            #pragma unroll
            for (int m2 = 7; m2 > 0; --m2) r[m2] = r[m2 - 1];
            r[0] = PACK_NEG_INF;
            hv = r[7];
        }
    }
}

// ---------------- kernel 0: prep (bf16 q/k + split fp16 V + log-rel) --------
__device__ __forceinline__ ushort f2bf(float f) {   // RNE
    unsigned u = __float_as_uint(f);
    return (ushort)((u + 0x7fffu + ((u >> 16) & 1u)) >> 16);
}
// kbp chunk C (16 B = 8 bf16): C = t16*256 + kc*64 + l
//   t16 = 16-slot tile (0..255), kc = K-chunk (0..3), l = lane
//   source = keys[slot = t16*16 + (l&15)][kc*32 + (l>>4)*8 .. +8)
// vh split: half d of V stored as vh[d*4096*512 + slot*512 + dim-in-half]
//   (each half = 4 MB fp16 -> fits one XCD's 4 MB L2)
#define QB_N  524288   // q bf16 convert, float4 granules
#define KBP_N 65536    // k permuted bf16 chunks
#define LR_N  4096     // log-reliability
#define VH_N  524288   // V fp16 convert, 8 floats per thread
__global__ void prep_kernel(const float* __restrict__ q, const float* __restrict__ k,
                            const float* __restrict__ rel, const float* __restrict__ v,
                            ushort* __restrict__ qb, ushort* __restrict__ kbp,
                            float* __restrict__ lr, ushort* __restrict__ vh) {
    int gid = blockIdx.x * 256 + threadIdx.x;
    if (gid < QB_N) {                         // qb row-major: 2,097,152 floats / 4
        float4 vv = ((const float4*)q)[gid];
        ushort4 o; o.x = f2bf(vv.x); o.y = f2bf(vv.y); o.z = f2bf(vv.z); o.w = f2bf(vv.w);
        ((ushort4*)qb)[gid] = o;
    } else if (gid < QB_N + KBP_N) {          // kbp fragment-permuted chunks
        int C = gid - QB_N;
        int l = C & 63, kc = (C >> 6) & 3, t16 = C >> 8;
        int slot = t16 * 16 + (l & 15);
        int doff = kc * 32 + (l >> 4) * 8;
        const float4* src = (const float4*)(k + (size_t)slot * DIM + doff);
        float4 v0 = src[0], v1 = src[1];
        union { ushort u[8]; uint4 v; } o;
        o.u[0] = f2bf(v0.x); o.u[1] = f2bf(v0.y); o.u[2] = f2bf(v0.z); o.u[3] = f2bf(v0.w);
        o.u[4] = f2bf(v1.x); o.u[5] = f2bf(v1.y); o.u[6] = f2bf(v1.z); o.u[7] = f2bf(v1.w);
        ((uint4*)kbp)[C] = o.v;
    } else if (gid < QB_N + KBP_N + LR_N) {
        int g = gid - QB_N - KBP_N;
        lr[g] = logf(rel[g] + REPS);
    } else if (gid < QB_N + KBP_N + LR_N + VH_N) {   // V fp32 -> fp16, dim-split
        int g = gid - QB_N - KBP_N - LR_N;
        int slot = g >> 7;
        int d0   = (g & 127) * 8;
        const float4* src = (const float4*)v + (size_t)g * 2;
        float4 a = src[0], b = src[1];
        union { _Float16 h[8]; uint4 u; } o;
        o.h[0] = (_Float16)a.x; o.h[1] = (_Float16)a.y;
        o.h[2] = (_Float16)a.z; o.h[3] = (_Float16)a.w;
        o.h[4] = (_Float16)b.x; o.h[5] = (_Float16)b.y;
        o.h[6] = (_Float16)b.z; o.h[7] = (_Float16)b.w;
        size_t didx = (d0 < 512)
            ? ((size_t)slot * 64 + (d0 >> 3))
            : ((size_t)4096 * 64 + (size_t)slot * 64 + ((d0 - 512) >> 3));
        ((uint4*)vh)[didx] = o.u;
    }
}

// ---------------- kernel 1: MFMA router + packed top-8 ----------------------
// Grid 1024 x 256 thr (4 waves): block = (token-group, slot-HALF). Each block
// scores 32 tokens x 2048 slots; wave w = 512 slots (32 tiles of 16). K tiles
// staged to PER-WAVE LDS double-buffers via global_load_lds, counted
// s_waitcnt vmcnt(4), NO in-loop barriers (proven discipline from round 5).
// Key change vs round 5: grid 512->1024 blocks -> 4 blocks/CU -> 4 waves/SIMD
// (was 2) for 2x latency hiding at identical total work / kbp traffic.
// Output: per-half sorted top-16 PACKED floats -> cpool[token][half*16+..].
// No cross-half merge: rescue re-sorts the 32-pool (halves are disjoint).
__launch_bounds__(256, 4)
__global__ void route_kernel(const ushort* __restrict__ qb,
                             const ushort* __restrict__ kbp,
                             const float*  __restrict__ lr,
                             float* __restrict__ cpool) {
    __shared__ ushort ktile[4][2][2048];      // [wave][buf][4KB tile] = 32 KB
    __shared__ float  qS[32][4][16];          // [token][quarter][16] = 8 KB
    const int tid  = threadIdx.x;
    const int lane = tid & 63;
    const int w    = tid >> 6;     // wave = slot quarter-of-half 0..3
    const int m    = lane & 15;    // token col
    const int kseg = lane >> 4;
    const int tg   = blockIdx.x >> 1;
    const int half = blockIdx.x & 1;
    const int tokbase = tg * 32;
    const int tilebase = half * 128 + w * 32;   // global 16-slot tile id

    // stationary B-frags (queries) for both 16-token halves
    bf16x8 bF0[4], bF1[4];
    const ushort* q0 = qb + (size_t)(tokbase + m) * DIM + kseg * 8;
    const ushort* q1 = qb + (size_t)(tokbase + 16 + m) * DIM + kseg * 8;
    #pragma unroll
    for (int kc = 0; kc < 4; ++kc) {
        bF0[kc] = *(const bf16x8*)(q0 + kc * 32);
        bF1[kc] = *(const bf16x8*)(q1 + kc * 32);
    }

    float R0[8], R1[8];
    #pragma unroll
    for (int i = 0; i < 8; ++i) { R0[i] = PACK_NEG_INF; R1[i] = PACK_NEG_INF; }

    // DMA one 16-slot tile (4 KB = 4 chunks x 64 lanes x 16 B) into wave buf
    auto issue = [&](int t, int buf) {
        const ushort* gt = kbp + ((size_t)((tilebase + t) * 256 + lane)) * 8;
        ushort* lb = &ktile[w][buf][0];
        #pragma unroll
        for (int i = 0; i < 4; ++i) {
            __builtin_amdgcn_global_load_lds((as1cv)(gt + i * 512),
                                             (as3v)(lb + i * 512 + lane * 8), 16, 0, 0);
        }
    };

    issue(0, 0);
    issue(1, 1);

    for (int t = 0; t < 32; ++t) {
        const int cur = t & 1;
        if (t < 31) {
            asm volatile("s_waitcnt vmcnt(4)" ::: "memory");
        } else {
            asm volatile("s_waitcnt vmcnt(0)" ::: "memory");
        }
        const ushort* kt = &ktile[w][cur][0];
        bf16x8 aF[4];
        #pragma unroll
        for (int kc = 0; kc < 4; ++kc)
            aF[kc] = *(const bf16x8*)(kt + kc * 512 + lane * 8);
        asm volatile("s_waitcnt lgkmcnt(0)" ::: "memory");
        if (t < 30) issue(t + 2, cur);

        f32x4 acc0 = {0.f, 0.f, 0.f, 0.f};
        f32x4 acc1 = {0.f, 0.f, 0.f, 0.f};
        #pragma unroll
        for (int kc = 0; kc < 4; ++kc) {
            acc0 = __builtin_amdgcn_mfma_f32_16x16x32_bf16(aF[kc], bF0[kc], acc0, 0, 0, 0);
            acc1 = __builtin_amdgcn_mfma_f32_16x16x32_bf16(aF[kc], bF1[kc], acc1, 0, 0, 0);
        }
        const int base = half * 2048 + w * 512 + t * 16;
        float4 lrv = ((const float4*)lr)[(base >> 2) + kseg];
        unsigned invb = 4095u - (unsigned)(base + kseg * 4);
        ins_packed(R0, pack_score(acc0[0] + lrv.x, invb));
        ins_packed(R0, pack_score(acc0[1] + lrv.y, invb - 1));
        ins_packed(R0, pack_score(acc0[2] + lrv.z, invb - 2));
        ins_packed(R0, pack_score(acc0[3] + lrv.w, invb - 3));
        ins_packed(R1, pack_score(acc1[0] + lrv.x, invb));
        ins_packed(R1, pack_score(acc1[1] + lrv.y, invb - 1));
        ins_packed(R1, pack_score(acc1[2] + lrv.z, invb - 2));
        ins_packed(R1, pack_score(acc1[3] + lrv.w, invb - 3));
    }

    merge_out16(R0, kseg, &qS[m][w][0]);
    merge_out16(R1, kseg, &qS[m + 16][w][0]);
    __syncthreads();

    // 4-way merge of this half's quarter-lists -> half top-16, packed floats
    if (tid < 32) {
        const int token = tokbase + tid;
        int p[4] = {0, 0, 0, 0};
        #pragma unroll
        for (int c = 0; c < 16; ++c) {
            float bv = -INFINITY; int bq = 0;
            #pragma unroll
            for (int j = 0; j < 4; ++j) {
                float v = (p[j] < 16) ? qS[tid][j][p[j]] : -INFINITY;
                if (v > bv) { bv = v; bq = j; }
            }
            cpool[(size_t)token * 32 + half * 16 + c] = bv;
            ++p[bq];
        }
    }
}

// ---------------- kernel 2: fused fp32 rescue + softmax + V gather ----------
// Grid 8192 x 256 thr: block = (token-group of 4, output-dim HALF), wave =
// token. dhalf is derived from blockIdx&7 so (assuming round-robin block->XCD
// dispatch) XCDs 0-3 only touch V-half 0 and XCDs 4-7 only V-half 1: the
// per-XCD gather working set is 4 MB = exactly one L2 -> capacity misses
// (the round-3/5 2 TB/s wall at ~50% hit) mostly vanish. Wrong-mapping
// fallback: correctness unaffected, perf = status quo. out stores and query
// loads are NONTEMPORAL so the 67 MB write stream stops churning L2.
// Pool is now 32 packed floats (2 disjoint halves x 16): lane = cand(32) x
// dim-half-of-dot(2); exact fp32 re-rank via 32-wide bitonic (s desc, idx
// asc), softmax on raw scores, gather this block's 512-dim half of 8 rows.
__device__ __forceinline__ float2 h2f2(unsigned u) {
    return __half22float2(*reinterpret_cast<const __half2*>(&u));
}
__launch_bounds__(256)
__global__ void rescue_gather_kernel(const float* __restrict__ query,
                                     const float* __restrict__ keys,
                                     const float* __restrict__ lr,
                                     const float* __restrict__ cpool,
                                     const ushort* __restrict__ vh,
                                     float* __restrict__ out,
                                     float* __restrict__ wout) {
    const int tid  = threadIdx.x;
    const int wv   = tid >> 6;
    const int lane = tid & 63;
    const int b    = blockIdx.x;
    const int x    = b & 7;
    const int dhalf = x >> 2;                 // V/out dim-half (XCD-steered)
    const int tg   = (b >> 3) * 4 + (x & 3);  // token group 0..4095
    const int token = tg * 4 + wv;
    const int c  = lane >> 1;    // candidate 0..31
    const int h  = lane & 1;     // dot dim-half (64 floats)

    float pv = cpool[(size_t)token * 32 + c];
    int ci = 4095 - (int)(__float_as_uint(pv) & 0xFFFu);

    const f32x4* q4 = (const f32x4*)(query + (size_t)token * DIM + h * 64);
    const float4* k4 = (const float4*)(keys + (size_t)ci * DIM + h * 64);
    float sum = 0.f;
    #pragma unroll
    for (int i = 0; i < 16; ++i) {
        f32x4  a = __builtin_nontemporal_load(q4 + i);
        float4 bb = k4[i];
        sum = fmaf(a.x, bb.x, sum); sum = fmaf(a.y, bb.y, sum);
        sum = fmaf(a.z, bb.z, sum); sum = fmaf(a.w, bb.w, sum);
    }
    sum += __shfl_xor(sum, 1, 2);    // both twin lanes hold the full dot
    float raw = sum;
    float s   = sum + lr[ci];        // biased, exact fp32

    // bitonic sort of 32 candidates across lanes (twins mirror; partner lane
    // = lane ^ (j*2)). "mineFirst" = ranks before = (s desc, idx asc).
    #pragma unroll
    for (int k = 2; k <= 32; k <<= 1) {
        #pragma unroll
        for (int j = k >> 1; j >= 1; j >>= 1) {
            int off = j << 1;
            float s2 = __shfl_xor(s,   off, 64);
            float r2 = __shfl_xor(raw, off, 64);
            int   i2 = __shfl_xor(ci,  off, 64);
            bool mineFirst = (s > s2) || (s == s2 && ci < i2);
            bool lower = (c & j) == 0;
            bool asc   = (c & k) == 0;
            bool keep  = (lower == asc) ? mineFirst : !mineFirst;
            if (!keep) { s = s2; raw = r2; ci = i2; }
        }
    }
    // position c holds rank c; broadcast top-8 (raw, idx) to all lanes
    float rsel[8]; int isel[8];
    #pragma unroll
    for (int r = 0; r < 8; ++r) {
        rsel[r] = __shfl(raw, r * 2, 64);
        isel[r] = __shfl(ci,  r * 2, 64);
    }

    // softmax on raw*SCALE — redundantly in every lane (weights in registers)
    float mx = -INFINITY;
    #pragma unroll
    for (int k = 0; k < 8; ++k) { rsel[k] *= SCALE; mx = fmaxf(mx, rsel[k]); }
    float e[8]; float ssum = 0.f;
    #pragma unroll
    for (int k = 0; k < 8; ++k) { e[k] = expf(rsel[k] - mx); ssum += e[k]; }
    float inv = 1.0f / ssum;
    float wk[8];
    #pragma unroll
    for (int k = 0; k < 8; ++k) wk[k] = e[k] * inv;

    if (dhalf == 0 && lane == 0) {
        #pragma unroll
        for (int k = 0; k < 8; ++k) wout[(size_t)token * 8 + k] = wk[k];
    }

    // gather this block's 512-dim half: row-half = 64 lanes x uint4 (8 halfs);
    // lane owns dims [dhalf*512 + lane*8, +8)
    const uint4* vbase = (const uint4*)vh + (size_t)dhalf * 4096 * 64;
    float o[8];
    #pragma unroll
    for (int i = 0; i < 8; ++i) o[i] = 0.f;
    #pragma unroll
    for (int k = 0; k < 8; ++k) {
        const uint4 va = vbase[(size_t)isel[k] * 64 + lane];
        float wkk = wk[k];
        float2 f;
        f = h2f2(va.x); o[0] = fmaf(wkk, f.x, o[0]); o[1] = fmaf(wkk, f.y, o[1]);
        f = h2f2(va.y); o[2] = fmaf(wkk, f.x, o[2]); o[3] = fmaf(wkk, f.y, o[3]);
        f = h2f2(va.z); o[4] = fmaf(wkk, f.x, o[4]); o[5] = fmaf(wkk, f.y, o[5]);
        f = h2f2(va.w); o[6] = fmaf(wkk, f.x, o[6]); o[7] = fmaf(wkk, f.y, o[7]);
    }
    f32x4* orow = (f32x4*)(out + (size_t)token * HDIM + dhalf * 512 + lane * 8);
    f32x4 s0 = {o[0], o[1], o[2], o[3]};
    f32x4 s1 = {o[4], o[5], o[6], o[7]};
    __builtin_nontemporal_store(s0, orow);
    __builtin_nontemporal_store(s1, orow + 1);
}

// ---------------- launch ----------------
extern "C" void kernel_launch(void* const* d_in, const int* in_sizes, int n_in,
                              void* d_out, int out_size, void* d_ws, size_t ws_size,
                              hipStream_t stream) {
    const float* query  = (const float*)d_in[0];
    const float* keys   = (const float*)d_in[1];
    const float* values = (const float*)d_in[2];
    const float* rel    = (const float*)d_in[3];

    float* out  = (float*)d_out;                 // [16384, 1024]
    float* wout = out + (size_t)NTOK * HDIM;     // [16384, 8]

    char* ws = (char*)d_ws;
    float*  lr    = (float*)ws;   ws += 4096 * 4;                    // 16 KB
    ushort* qb    = (ushort*)ws;  ws += (size_t)NTOK * DIM * 2;      // 4 MB
    ushort* kbp   = (ushort*)ws;  ws += (size_t)NSLOTS * DIM * 2;    // 1 MB
    float*  cpool = (float*)ws;   ws += (size_t)NTOK * 32 * 4;       // 2 MB
    ushort* vh    = (ushort*)ws;                                     // 8 MB (2x4)

    int prep_grid = (QB_N + KBP_N + LR_N + VH_N) / 256;   // = 4368
    hipLaunchKernelGGL(prep_kernel, dim3(prep_grid), dim3(256), 0, stream,
                       query, keys, rel, values, qb, kbp, lr, vh);
    hipLaunchKernelGGL(route_kernel, dim3(NTOK / 16), dim3(256), 0, stream,
                       qb, kbp, lr, cpool);
    hipLaunchKernelGGL(rescue_gather_kernel, dim3(NTOK / 2), dim3(256), 0, stream,
                       query, keys, lr, cpool, vh, out, wout);
}

// Round 7
// 189.476 us; speedup vs baseline: 1.5034x; 1.5034x over previous
//
#include <hip/hip_runtime.h>
#include <hip/hip_fp16.h>
#include <math.h>

#define NSLOTS 4096
#define DIM    128
#define HDIM   1024
#define NTOK   16384   // 4 * 4096
#define SCALE  0.08838834764831845f  // 1/sqrt(128)
#define REPS   1e-10f

typedef __attribute__((ext_vector_type(8))) short bf16x8;
typedef __attribute__((ext_vector_type(4))) float f32x4;

// ---- packed (score | 4095-slot) helpers -----------------------------------
// Low 12 mantissa bits replaced by (4095-slot): float compare = score desc,
// then slot asc. fp32 rescue re-ranks the 16-candidate pool exactly, so only
// pool membership matters. Top-8-per-lane guarantees the true bf16-top-8 is
// always in the pool (≤7 elements outrank it anywhere).
__device__ __forceinline__ float pack_score(float biased, unsigned inv_idx) {
    return __uint_as_float((__float_as_uint(biased) & 0xFFFFF000u) | inv_idx);
}
#define PACK_NEG_INF __uint_as_float(0xFF7FF000u)   // ~ -FLT_MAX, valid finite

// Branchless insert into ascending sorted r[0..7] (r[7]=max), drop min.
__device__ __forceinline__ void ins_packed(float (&r)[8], float x) {
    #pragma unroll
    for (int i = 0; i < 7; ++i) r[i] = __builtin_amdgcn_fmed3f(r[i], x, r[i + 1]);
    r[7] = fmaxf(r[7], x);
}

// Pop-merge 4 kseg-lanes' sorted top-8 (32 values) -> sorted top-16 (desc,
// packed) into LDS. Group = lanes {l, l^16, l^32, l^48}.
__device__ __forceinline__ void merge_out16(float (&r)[8], int kseg, float* outS) {
    float hv = r[7];
    #pragma unroll
    for (int rnd = 0; rnd < 16; ++rnd) {
        float bv = hv;
        bv = fmaxf(bv, __shfl_xor(bv, 16, 64));
        bv = fmaxf(bv, __shfl_xor(bv, 32, 64));
        if ((rnd >> 2) == kseg) outS[rnd] = bv;   // each kseg-lane writes 4
        if (hv == bv) {   // my head won (packed values distinct in group): pop
            #pragma unroll
            for (int m2 = 7; m2 > 0; --m2) r[m2] = r[m2 - 1];
            r[0] = PACK_NEG_INF;
            hv = r[7];
        }
    }
}

// ---------------- kernel 0: prep (bf16 q/k + split fp16 V + log-rel) --------
__device__ __forceinline__ ushort f2bf(float f) {   // RNE
    unsigned u = __float_as_uint(f);
    return (ushort)((u + 0x7fffu + ((u >> 16) & 1u)) >> 16);
}
// kbp chunk C (16 B = 8 bf16): C = t16*256 + kc*64 + l
//   t16 = 16-slot tile (0..255), kc = K-chunk (0..3), l = lane
//   source = keys[slot = t16*16 + (l&15)][kc*32 + (l>>4)*8 .. +8)
// vh split: half d of V stored at vh[d*4096*512 + slot*512 + dim-in-half]
//   (each half = 4 MB fp16 -> fits one XCD's 4 MB L2)
#define QB_N  524288   // q bf16 convert, float4 granules
#define KBP_N 65536    // k permuted bf16 chunks
#define LR_N  4096     // log-reliability
#define VH_N  524288   // V fp32 -> fp16 convert, 8 floats per thread
__global__ void prep_kernel(const float* __restrict__ q, const float* __restrict__ k,
                            const float* __restrict__ rel, const float* __restrict__ v,
                            ushort* __restrict__ qb, ushort* __restrict__ kbp,
                            float* __restrict__ lr, ushort* __restrict__ vh) {
    int gid = blockIdx.x * 256 + threadIdx.x;
    if (gid < QB_N) {                         // qb row-major: 2,097,152 floats / 4
        float4 vv = ((const float4*)q)[gid];
        ushort4 o; o.x = f2bf(vv.x); o.y = f2bf(vv.y); o.z = f2bf(vv.z); o.w = f2bf(vv.w);
        ((ushort4*)qb)[gid] = o;
    } else if (gid < QB_N + KBP_N) {          // kbp fragment-permuted chunks
        int C = gid - QB_N;
        int l = C & 63, kc = (C >> 6) & 3, t16 = C >> 8;
        int slot = t16 * 16 + (l & 15);
        int doff = kc * 32 + (l >> 4) * 8;
        const float4* src = (const float4*)(k + (size_t)slot * DIM + doff);
        float4 v0 = src[0], v1 = src[1];
        union { ushort u[8]; uint4 v; } o;
        o.u[0] = f2bf(v0.x); o.u[1] = f2bf(v0.y); o.u[2] = f2bf(v0.z); o.u[3] = f2bf(v0.w);
        o.u[4] = f2bf(v1.x); o.u[5] = f2bf(v1.y); o.u[6] = f2bf(v1.z); o.u[7] = f2bf(v1.w);
        ((uint4*)kbp)[C] = o.v;
    } else if (gid < QB_N + KBP_N + LR_N) {
        int g = gid - QB_N - KBP_N;
        lr[g] = logf(rel[g] + REPS);
    } else if (gid < QB_N + KBP_N + LR_N + VH_N) {   // V fp32 -> fp16, dim-split
        int g = gid - QB_N - KBP_N - LR_N;
        int slot = g >> 7;
        int d0   = (g & 127) * 8;
        const float4* src = (const float4*)v + (size_t)g * 2;
        float4 a = src[0], b = src[1];
        union { _Float16 h[8]; uint4 u; } o;
        o.h[0] = (_Float16)a.x; o.h[1] = (_Float16)a.y;
        o.h[2] = (_Float16)a.z; o.h[3] = (_Float16)a.w;
        o.h[4] = (_Float16)b.x; o.h[5] = (_Float16)b.y;
        o.h[6] = (_Float16)b.z; o.h[7] = (_Float16)b.w;
        size_t didx = (d0 < 512)
            ? ((size_t)slot * 64 + (d0 >> 3))
            : ((size_t)4096 * 64 + (size_t)slot * 64 + ((d0 - 512) >> 3));
        ((uint4*)vh)[didx] = o.u;
    }
}

// ---------------- kernel 1: MFMA router + packed top-8 ----------------------
// (round-3 proven version) Grid 512 x 512 thr (8 waves). Block = 32 tokens,
// all 4096 slots; wave w = slot eighth (512 slots = 32 tiles of 16), K tiles
// in REGISTERS loaded from L2 (kbp 1 MB, L2-resident) — no LDS staging, no
// in-loop barriers, explicit next-tile prefetch. Each tile feeds TWO 16-token
// MFMA column blocks. Per-lane top-8 over its 128-slot partition; 4-lane
// merge -> eighth top-16; 8-way merge -> global top-16 pool -> cand.
__launch_bounds__(512, 4)
__global__ void route_kernel(const ushort* __restrict__ qb,
                             const ushort* __restrict__ kbp,
                             const float*  __restrict__ lr,
                             int* __restrict__ cand) {
    __shared__ float qS[32][8][17];   // [token][eighth][16 +1 pad] = 17 KB
    const int tid  = threadIdx.x;
    const int lane = tid & 63;
    const int w    = tid >> 6;     // wave = slot eighth 0..7
    const int m    = lane & 15;    // token col
    const int kseg = lane >> 4;
    const int tokbase = blockIdx.x * 32;

    // stationary B-frags (queries) for both 16-token halves
    bf16x8 bF0[4], bF1[4];
    const ushort* q0 = qb + (size_t)(tokbase + m) * DIM + kseg * 8;
    const ushort* q1 = qb + (size_t)(tokbase + 16 + m) * DIM + kseg * 8;
    #pragma unroll
    for (int kc = 0; kc < 4; ++kc) {
        bF0[kc] = *(const bf16x8*)(q0 + kc * 32);
        bF1[kc] = *(const bf16x8*)(q1 + kc * 32);
    }

    float R0[8], R1[8];
    #pragma unroll
    for (int i = 0; i < 8; ++i) { R0[i] = PACK_NEG_INF; R1[i] = PACK_NEG_INF; }

    const uint4* kb4 = (const uint4*)kbp;
    const int tbase = w * 32;   // this wave's first global 16-slot tile

    uint4 A[4], N[4];
    #pragma unroll
    for (int kc = 0; kc < 4; ++kc)
        A[kc] = kb4[(size_t)tbase * 256 + kc * 64 + lane];

    for (int t = 0; t < 32; ++t) {
        if (t < 31) {
            #pragma unroll
            for (int kc = 0; kc < 4; ++kc)
                N[kc] = kb4[(size_t)(tbase + t + 1) * 256 + kc * 64 + lane];
        }
        f32x4 acc0 = {0.f, 0.f, 0.f, 0.f};
        f32x4 acc1 = {0.f, 0.f, 0.f, 0.f};
        #pragma unroll
        for (int kc = 0; kc < 4; ++kc) {
            bf16x8 aF = *(const bf16x8*)&A[kc];
            acc0 = __builtin_amdgcn_mfma_f32_16x16x32_bf16(aF, bF0[kc], acc0, 0, 0, 0);
            acc1 = __builtin_amdgcn_mfma_f32_16x16x32_bf16(aF, bF1[kc], acc1, 0, 0, 0);
        }
        const int base = w * 512 + t * 16;
        float4 lrv = ((const float4*)lr)[(base >> 2) + kseg];
        unsigned invb = 4095u - (unsigned)(base + kseg * 4);
        ins_packed(R0, pack_score(acc0[0] + lrv.x, invb));
        ins_packed(R0, pack_score(acc0[1] + lrv.y, invb - 1));
        ins_packed(R0, pack_score(acc0[2] + lrv.z, invb - 2));
        ins_packed(R0, pack_score(acc0[3] + lrv.w, invb - 3));
        ins_packed(R1, pack_score(acc1[0] + lrv.x, invb));
        ins_packed(R1, pack_score(acc1[1] + lrv.y, invb - 1));
        ins_packed(R1, pack_score(acc1[2] + lrv.z, invb - 2));
        ins_packed(R1, pack_score(acc1[3] + lrv.w, invb - 3));
        #pragma unroll
        for (int kc = 0; kc < 4; ++kc) A[kc] = N[kc];
    }

    merge_out16(R0, kseg, &qS[m][w][0]);
    merge_out16(R1, kseg, &qS[m + 16][w][0]);
    __syncthreads();

    // 8-way merge of the eighths' sorted-desc lists -> exact global top-16
    if (tid < 32) {
        const int token = tokbase + tid;
        int p[8] = {0, 0, 0, 0, 0, 0, 0, 0};
        #pragma unroll
        for (int c = 0; c < 16; ++c) {
            float bv = -INFINITY; int bq = 0;
            #pragma unroll
            for (int j = 0; j < 8; ++j) {
                float v = (p[j] < 16) ? qS[tid][j][p[j]] : -INFINITY;
                if (v > bv) { bv = v; bq = j; }
            }
            cand[(size_t)token * 16 + c] = 4095 - (int)(__float_as_uint(bv) & 0xFFFu);
            ++p[bq];
        }
    }
}

// ---------------- kernel 2a: fp32 rescue score (no gather) ------------------
// 1 wave per token (4/block); lane = cand(16) x dim-quarter(4). Exact fp32
// q.k on the 16-candidate pool; 16-wide bitonic (s desc, idx asc — same rank
// order as reference top_k); softmax on raw scores. Writes weights (wout) and
// the 8 selected indices (isel) — gather runs in its own kernel so the
// ~1500-cycle serial sort chain never sits in front of the V loads.
__launch_bounds__(256)
__global__ void score_kernel(const float* __restrict__ query,
                             const float* __restrict__ keys,
                             const float* __restrict__ lr,
                             const int*   __restrict__ cand,
                             int*   __restrict__ iselg,
                             float* __restrict__ wout) {
    const int tid  = threadIdx.x;
    const int w    = tid >> 6;
    const int lane = tid & 63;
    const int token = blockIdx.x * 4 + w;
    const int c  = lane >> 2;    // candidate 0..15
    const int qp = lane & 3;     // dim quarter (32 floats)

    int ci = cand[(size_t)token * 16 + c];
    const float4* q4 = (const float4*)(query + (size_t)token * DIM) + qp * 8;
    const float4* k4 = (const float4*)(keys  + (size_t)ci    * DIM) + qp * 8;
    float sum = 0.f;
    #pragma unroll
    for (int i = 0; i < 8; ++i) {
        float4 a = q4[i], b = k4[i];
        sum = fmaf(a.x, b.x, sum); sum = fmaf(a.y, b.y, sum);
        sum = fmaf(a.z, b.z, sum); sum = fmaf(a.w, b.w, sum);
    }
    sum += __shfl_xor(sum, 1, 4);
    sum += __shfl_xor(sum, 2, 4);    // all 4 twins hold the full dot
    float raw = sum;
    float s   = sum + lr[ci];        // biased, exact fp32

    // bitonic sort of 16 candidates across lanes (twins mirror; partner lane
    // = lane ^ (j*4)). "mineFirst" = ranks before = (s desc, idx asc).
    #pragma unroll
    for (int k = 2; k <= 16; k <<= 1) {
        #pragma unroll
        for (int j = k >> 1; j >= 1; j >>= 1) {
            int off = j << 2;
            float s2 = __shfl_xor(s,   off, 64);
            float r2 = __shfl_xor(raw, off, 64);
            int   i2 = __shfl_xor(ci,  off, 64);
            bool mineFirst = (s > s2) || (s == s2 && ci < i2);
            bool lower = (c & j) == 0;
            bool asc   = (c & k) == 0;
            bool keep  = (lower == asc) ? mineFirst : !mineFirst;
            if (!keep) { s = s2; raw = r2; ci = i2; }
        }
    }
    // position c now holds rank c; broadcast top-8 (raw, idx) to all lanes
    float rsel[8]; int isel[8];
    #pragma unroll
    for (int r = 0; r < 8; ++r) {
        rsel[r] = __shfl(raw, r * 4, 64);
        isel[r] = __shfl(ci,  r * 4, 64);
    }

    // softmax on raw*SCALE
    float mx = -INFINITY;
    #pragma unroll
    for (int k = 0; k < 8; ++k) { rsel[k] *= SCALE; mx = fmaxf(mx, rsel[k]); }
    float e[8]; float ssum = 0.f;
    #pragma unroll
    for (int k = 0; k < 8; ++k) { e[k] = expf(rsel[k] - mx); ssum += e[k]; }
    float inv = 1.0f / ssum;

    if (lane == 0) {
        float4* wo = (float4*)(wout + (size_t)token * 8);
        wo[0] = make_float4(e[0] * inv, e[1] * inv, e[2] * inv, e[3] * inv);
        wo[1] = make_float4(e[4] * inv, e[5] * inv, e[6] * inv, e[7] * inv);
        int4* io = (int4*)(iselg + (size_t)token * 8);
        io[0] = make_int4(isel[0], isel[1], isel[2], isel[3]);
        io[1] = make_int4(isel[4], isel[5], isel[6], isel[7]);
    }
}

// ---------------- kernel 2b: XCD-steered pure V gather ----------------------
// Grid 8192 x 256 thr: block = (token-group of 4, output-dim HALF); wave =
// token. dhalf = (blockIdx&7)>>2 so with round-robin block->XCD dispatch,
// XCDs 0-3 touch only V-half 0 and XCDs 4-7 only V-half 1: per-XCD gather
// working set = 4 MB = one L2 (r6's FETCH drop validated the steering; r6's
// regression came from fusing score into both halves — removed here).
// Per lane: 8 INDEPENDENT 16-B loads issued back-to-back, then accumulate.
// out stores nontemporal (write stream must not churn the V-resident L2).
__device__ __forceinline__ float2 h2f2(unsigned u) {
    return __half22float2(*reinterpret_cast<const __half2*>(&u));
}
__launch_bounds__(256)
__global__ void gather_kernel(const float* __restrict__ wout,
                              const int*   __restrict__ iselg,
                              const ushort* __restrict__ vh,
                              float* __restrict__ out) {
    const int tid  = threadIdx.x;
    const int wv   = tid >> 6;
    const int lane = tid & 63;
    const int b    = blockIdx.x;
    const int x    = b & 7;
    const int dhalf = x >> 2;                 // V/out dim-half (XCD-steered)
    const int tg   = (b >> 3) * 4 + (x & 3);  // token group 0..4095
    const int token = tg * 4 + wv;

    const float4* wo = (const float4*)(wout + (size_t)token * 8);
    const int4*   io = (const int4*)(iselg + (size_t)token * 8);
    float4 w0 = wo[0], w1 = wo[1];
    int4   i0 = io[0], i1 = io[1];

    const uint4* vbase = (const uint4*)vh + (size_t)dhalf * 4096 * 64;
    // issue all 8 gathers first (independent), then accumulate
    uint4 va[8];
    va[0] = vbase[(size_t)i0.x * 64 + lane];
    va[1] = vbase[(size_t)i0.y * 64 + lane];
    va[2] = vbase[(size_t)i0.z * 64 + lane];
    va[3] = vbase[(size_t)i0.w * 64 + lane];
    va[4] = vbase[(size_t)i1.x * 64 + lane];
    va[5] = vbase[(size_t)i1.y * 64 + lane];
    va[6] = vbase[(size_t)i1.z * 64 + lane];
    va[7] = vbase[(size_t)i1.w * 64 + lane];
    float wk[8] = {w0.x, w0.y, w0.z, w0.w, w1.x, w1.y, w1.z, w1.w};

    float o[8];
    #pragma unroll
    for (int i = 0; i < 8; ++i) o[i] = 0.f;
    #pragma unroll
    for (int k = 0; k < 8; ++k) {
        float wkk = wk[k];
        float2 f;
        f = h2f2(va[k].x); o[0] = fmaf(wkk, f.x, o[0]); o[1] = fmaf(wkk, f.y, o[1]);
        f = h2f2(va[k].y); o[2] = fmaf(wkk, f.x, o[2]); o[3] = fmaf(wkk, f.y, o[3]);
        f = h2f2(va[k].z); o[4] = fmaf(wkk, f.x, o[4]); o[5] = fmaf(wkk, f.y, o[5]);
        f = h2f2(va[k].w); o[6] = fmaf(wkk, f.x, o[6]); o[7] = fmaf(wkk, f.y, o[7]);
    }
    f32x4* orow = (f32x4*)(out + (size_t)token * HDIM + dhalf * 512 + lane * 8);
    f32x4 s0 = {o[0], o[1], o[2], o[3]};
    f32x4 s1 = {o[4], o[5], o[6], o[7]};
    __builtin_nontemporal_store(s0, orow);
    __builtin_nontemporal_store(s1, orow + 1);
}

// ---------------- launch ----------------
extern "C" void kernel_launch(void* const* d_in, const int* in_sizes, int n_in,
                              void* d_out, int out_size, void* d_ws, size_t ws_size,
                              hipStream_t stream) {
    const float* query  = (const float*)d_in[0];
    const float* keys   = (const float*)d_in[1];
    const float* values = (const float*)d_in[2];
    const float* rel    = (const float*)d_in[3];

    float* out  = (float*)d_out;                 // [16384, 1024]
    float* wout = out + (size_t)NTOK * HDIM;     // [16384, 8]

    char* ws = (char*)d_ws;
    float*  lr    = (float*)ws;   ws += 4096 * 4;                    // 16 KB
    ushort* qb    = (ushort*)ws;  ws += (size_t)NTOK * DIM * 2;      // 4 MB
    ushort* kbp   = (ushort*)ws;  ws += (size_t)NSLOTS * DIM * 2;    // 1 MB
    int*    cand  = (int*)ws;     ws += (size_t)NTOK * 16 * 4;       // 1 MB
    int*    iselg = (int*)ws;     ws += (size_t)NTOK * 8 * 4;        // 0.5 MB
    ushort* vh    = (ushort*)ws;                                     // 8 MB (2x4)

    int prep_grid = (QB_N + KBP_N + LR_N + VH_N) / 256;   // = 4368
    hipLaunchKernelGGL(prep_kernel, dim3(prep_grid), dim3(256), 0, stream,
                       query, keys, rel, values, qb, kbp, lr, vh);
    hipLaunchKernelGGL(route_kernel, dim3(NTOK / 32), dim3(512), 0, stream,
                       qb, kbp, lr, cand);
    hipLaunchKernelGGL(score_kernel, dim3(NTOK / 4), dim3(256), 0, stream,
                       query, keys, lr, cand, iselg, wout);
    hipLaunchKernelGGL(gather_kernel, dim3(NTOK / 2), dim3(256), 0, stream,
                       wout, iselg, vh, out);
}